// Round 13
// baseline (198.629 us; speedup 1.0000x reference)
//
#include <hip/hip_runtime.h>
#include <hip/hip_bf16.h>
#include <math.h>

#define B_ 32
#define S_ 1024
#define E_ 512
#define T_ 128
#define Q_ 256
#define H_ 4
#define F_ (H_ * Q_)      // 1024
#define M_ (B_ * S_)      // 32768

typedef _Float16 f16x8 __attribute__((ext_vector_type(8)));
typedef float f32x4 __attribute__((ext_vector_type(4)));
typedef unsigned int uint32;

__device__ __forceinline__ float lrelu(float x) { return x > 0.0f ? x : 0.01f * x; }

__device__ __forceinline__ uint32 packh2(float a, float b) {
    union { _Float16 h[2]; uint32 u; } v;
    v.h[0] = (_Float16)a; v.h[1] = (_Float16)b;
    return v.u;
}
__device__ __forceinline__ unsigned short packh1(float a) {
    union { _Float16 h; unsigned short u; } v;
    v.h = (_Float16)a;
    return v.u;
}
// 8 fp32 -> f16x8 via RTN casts (bit-identical to prep's packh2 path)
__device__ __forceinline__ f16x8 cvt8(float4 a, float4 b) {
    f16x8 r;
    r[0] = (_Float16)a.x; r[1] = (_Float16)a.y; r[2] = (_Float16)a.z; r[3] = (_Float16)a.w;
    r[4] = (_Float16)b.x; r[5] = (_Float16)b.y; r[6] = (_Float16)b.z; r[7] = (_Float16)b.w;
    return r;
}

#define GLOAD_LDS16(g, l)                                                       \
    __builtin_amdgcn_global_load_lds(                                           \
        (const __attribute__((address_space(1))) void*)(g),                     \
        (__attribute__((address_space(3))) void*)(l), 16, 0, 0)

#define WW_BLOCKS   128       // W_src windows / 64
#define HS_BLOCKS   1024      // head-select: wave per (t,b), 4 waves/block

// ---------------------------------------------------------------------------
// Prep (tiny — src untouched): pack W_src IN PLACE to fp16 (RTN) per 64-float
// window (64 fp16 in the window's first 128B); 4 lanes/window, wave-lockstep
// in-place-safe (r8/r9-proven). + per-(t,b) argmax head. The src fp16-pack
// pass is DELETED: proj reads raw fp32 A and converts in-register (r5-config
// measured non-proj = 69.7 us vs ~107 with the src pack).
// ---------------------------------------------------------------------------
__global__ __launch_bounds__(256) void prep_kernel(
    float* wsrc,
    const float* __restrict__ qv, const float* __restrict__ Wopt,
    int* __restrict__ best) {
    const int blk = blockIdx.x;
    if (blk < WW_BLOCKS) {
        const size_t w0 = (size_t)blk * 64;
        const int tid = threadIdx.x;
        const size_t c = w0 + (tid >> 2);
        const int j = tid & 3;
        const float* rp = wsrc + c * 64 + j * 16;
        float4 v0 = ((const float4*)rp)[0];
        float4 v1 = ((const float4*)rp)[1];
        float4 v2 = ((const float4*)rp)[2];
        float4 v3 = ((const float4*)rp)[3];
        uint4 o0 = make_uint4(packh2(v0.x, v0.y), packh2(v0.z, v0.w),
                              packh2(v1.x, v1.y), packh2(v1.z, v1.w));
        uint4 o1 = make_uint4(packh2(v2.x, v2.y), packh2(v2.z, v2.w),
                              packh2(v3.x, v3.y), packh2(v3.z, v3.w));
        char* op = (char*)(wsrc + c * 64) + j * 32;
        ((uint4*)op)[0] = o0;
        ((uint4*)op)[1] = o1;
    } else {
        const int wave = threadIdx.x >> 6, lane = threadIdx.x & 63;
        const int idx = (blk - WW_BLOCKS) * 4 + wave;   // t*B + b
        const float4 qq = *(const float4*)(qv + (size_t)idx * Q_ + lane * 4);
        float s[4];
#pragma unroll
        for (int h = 0; h < 4; ++h) {
            float4 w = *(const float4*)(Wopt + h * Q_ + lane * 4);
            s[h] = qq.x * w.x + qq.y * w.y + qq.z * w.z + qq.w * w.w;
        }
#pragma unroll
        for (int off = 32; off >= 1; off >>= 1) {
#pragma unroll
            for (int h = 0; h < 4; ++h) s[h] += __shfl_down(s[h], off);
        }
        if (lane == 0) {
            int bh = 0; float bs = s[0];
            if (s[1] > bs) { bs = s[1]; bh = 1; }
            if (s[2] > bs) { bs = s[2]; bh = 2; }
            if (s[3] > bs) { bs = s[3]; bh = 3; }
            best[idx] = bh;
        }
    }
}

// ---------------------------------------------------------------------------
// Fused proj+score, fp16, 128x256 tile — r12's verified A-direct structure,
// but A read as RAW FP32 (2 x float4 per frag) + RTN cvt in-register
// (bit-identical values to the packed path). Packed-frag element offset
// e0 = (ks>>1)*64 + (ks&1)*32 + quad*8 of row (wm*64+i*16+fr).
// Ledger: per step issue A(ks+1)[8 fp32 loads] then B(ks+2)[4 DMA].
// B(ks+1)-landed fencing before the end-of-step barrier is GUARANTEED by
// the compiler's ar-wait before CVT (A(ks+1) is newer than B(ks+1), waits
// are count-ordered). CVT placed post-MFMA behind sched_barrier(0) (r5's
// verified placement) so the ar-wait never stalls the MFMA cluster.
// Prologue: LOADA(0), B(0), B(1); CVT (waits A0); vmcnt(4) (B0 landed).
// B path, swizzle, epilogue verbatim r12 (passed, absmax 0.0078125).
// ---------------------------------------------------------------------------
__global__ __launch_bounds__(256, 2) void proj_score_kernel(
    const float* __restrict__ Af,            // RAW fp32 src (B,S,E) — read-only
    const unsigned char* __restrict__ Wpk,   // fp16-packed W_src (windowed)
    const float* __restrict__ qv,            // (T,B,Q) fp32
    const int* __restrict__ best,            // (T*B)
    float* __restrict__ bufs)                // (T,B,S) logits in ws
{
    __shared__ uint4 smem4[4800];            // 76800 B
    char* smem = (char*)smem4;
    // K-loop dbuf (B only): buf@0, buf@16384; each 16KB (256 rows x 64B)
    // Epilogue: P @0 (128 rows x 512B = 64KB)  Q @65536 (16 rows x 512B = 8KB)
    //           tl @73728 (+512)  lcnt @74240

    const int bid = blockIdx.x;
    const int xcd = bid & 7;
    const int q_ = bid >> 3;                 // 0..127 within XCD
    const int bi = xcd * 32 + (q_ >> 2);     // 0..255 (M tile, 128 rows)
    const int bj = q_ & 3;                   // head 0..3 (N tile, 256 cols)

    const int tid = threadIdx.x;
    const int wave = tid >> 6, lane = tid & 63;
    const int wm = wave >> 1, wn = wave & 1;
    const int quad = lane >> 4;
    const int fr = lane & 15;
    const int xr = fr & 7;

    const size_t Wbase = (size_t)(bj * 256) * 2048;

    // --- B staging lane mapping (16 rows x 4 slots per wave-instr) ---
    const int r16 = lane >> 2;
    const int slot = lane & 3;
    const int sgb = ((slot ^ ((r16 >> 1) & 3)) & 3) * 16;  // pre-swizzled src group
    const unsigned char* gW = Wpk + Wbase + (size_t)(wave * 64 + r16) * 2048 + sgb;

    // --- A raw fp32 fragment base: row (wm*64+fr), element quad*8 ---
    const float* gAfF = Af + (size_t)(bi * 128 + wm * 64 + fr) * 512 + quad * 8;

    // --- compute lane mapping (B frag reads) ---
    const int koB = ((quad ^ ((fr >> 1) & 3)) & 3) * 16;   // swizzled read slot
    const int boff = (wn * 128 + fr) * 64 + koB;

    f32x4 acc[4][8] = {};
    f16x8 ah[4];
    float4 ar0, ar1, ar2, ar3, ar4, ar5, ar6, ar7;   // raw A in flight (named, static)

#define STAGE_B(bufb_, ks_) do {                                               \
    const int hb_ = ((ks_) >> 1) * 256 + ((ks_) & 1) * 64;                     \
    _Pragma("unroll")                                                          \
    for (int c_ = 0; c_ < 4; ++c_) {                                           \
        GLOAD_LDS16(gW + (size_t)c_ * 16 * 2048 + hb_,                         \
                    smem + (bufb_) + (wave * 4 + c_) * 1024);                  \
    }                                                                          \
} while (0)

#define LOADA_RAW(ks_) do {                                                    \
    const float* p_ = gAfF + ((ks_) >> 1) * 64 + ((ks_) & 1) * 32;             \
    ar0 = *(const float4*)(p_);                                                \
    ar1 = *(const float4*)(p_ + 4);                                            \
    ar2 = *(const float4*)(p_ + 8192);                                         \
    ar3 = *(const float4*)(p_ + 8196);                                         \
    ar4 = *(const float4*)(p_ + 16384);                                        \
    ar5 = *(const float4*)(p_ + 16388);                                        \
    ar6 = *(const float4*)(p_ + 24576);                                        \
    ar7 = *(const float4*)(p_ + 24580);                                        \
} while (0)

#define CVT_AH() do {                                                          \
    ah[0] = cvt8(ar0, ar1);                                                    \
    ah[1] = cvt8(ar2, ar3);                                                    \
    ah[2] = cvt8(ar4, ar5);                                                    \
    ah[3] = cvt8(ar6, ar7);                                                    \
} while (0)

#define KSTEP(ks_) do {                                                        \
    const int ksv_ = (ks_);                                                    \
    f16x8 bh8[8];                                                              \
    _Pragma("unroll")                                                          \
    for (int j_ = 0; j_ < 8; ++j_)                                             \
        bh8[j_] = *(const f16x8*)(smem + cur + boff + j_ * 1024);              \
    asm volatile("s_waitcnt lgkmcnt(0)" ::: "memory");                         \
    __builtin_amdgcn_s_barrier();                                              \
    if (ksv_ <= 14) LOADA_RAW(ksv_ + 1);                                       \
    if (ksv_ <= 13) STAGE_B(cur, ksv_ + 2);                                    \
    __builtin_amdgcn_sched_barrier(0);                                         \
    __builtin_amdgcn_s_setprio(1);                                             \
    _Pragma("unroll")                                                          \
    for (int i_ = 0; i_ < 4; ++i_)                                             \
        _Pragma("unroll")                                                      \
        for (int j_ = 0; j_ < 8; ++j_)                                         \
            acc[i_][j_] = __builtin_amdgcn_mfma_f32_16x16x32_f16(ah[i_], bh8[j_], acc[i_][j_], 0, 0, 0); \
    __builtin_amdgcn_s_setprio(0);                                             \
    __builtin_amdgcn_sched_barrier(0);                                         \
    if (ksv_ <= 14) { CVT_AH(); }       /* compiler ar-wait lands HERE */      \
    if (ksv_ <= 14) __builtin_amdgcn_s_barrier();                              \
    cur ^= 16384;                                                              \
} while (0)

    LOADA_RAW(0);
    STAGE_B(0, 0);
    STAGE_B(16384, 1);
    CVT_AH();                                          // waits A(0); B0,B1 fly
    asm volatile("s_waitcnt vmcnt(4)" ::: "memory");   // B(0) landed (B1 fly)
    __builtin_amdgcn_s_barrier();

    int cur = 0;
#pragma unroll 1
    for (int ks = 0; ks < 16; ++ks) {
        KSTEP(ks);
    }

#undef STAGE_B
#undef LOADA_RAW
#undef CVT_AH
#undef KSTEP

    // ---- fused score epilogue (r12-verbatim) ----
    const int b = bi >> 3;
    const int sbase = (bi & 7) * 128;

    __syncthreads();                       // K-loop LDS reads done
    int* tl = (int*)(smem + 73728);
    int* lcnt = (int*)(smem + 74240);
    if (tid == 0) *lcnt = 0;
    __syncthreads();
    if (tid < 128) {
        if (best[tid * B_ + b] == bj) {
            int slot2 = atomicAdd(lcnt, 1);   // LDS atomic
            tl[slot2] = tid;
        }
    }
    __syncthreads();
    const int n = *lcnt;

    // P write: every wave writes its own acc (P covers all 128 rows at once)
#pragma unroll
    for (int i = 0; i < 4; ++i) {
#pragma unroll
        for (int j = 0; j < 8; ++j) {
            int col = wn * 128 + j * 16 + fr;
            int g = col >> 3;
            int cb = (col & 7) * 2;
#pragma unroll
            for (int r = 0; r < 4; ++r) {
                int rr = wm * 64 + i * 16 + quad * 4 + r;
                int gs = (g & 24) | ((g ^ rr) & 7);
                *(unsigned short*)(smem + rr * 512 + gs * 16 + cb) =
                    packh1(lrelu(acc[i][j][r]));
            }
        }
    }
    __syncthreads();

    const int t_idx = tid >> 4, seg = tid & 15;

    for (int tc = 0; tc < n; tc += 16) {
        int nn = min(16, n - tc);
        if (t_idx < nn) {
            int tt = tl[tc + t_idx];
            const float* qp = qv + ((size_t)tt * B_ + b) * Q_ + seg * 16;
            float4 f0 = *(const float4*)(qp);
            float4 f1 = *(const float4*)(qp + 4);
            float4 f2 = *(const float4*)(qp + 8);
            float4 f3 = *(const float4*)(qp + 12);
            uint4 h0 = make_uint4(packh2(f0.x, f0.y), packh2(f0.z, f0.w),
                                  packh2(f1.x, f1.y), packh2(f1.z, f1.w));
            uint4 h1 = make_uint4(packh2(f2.x, f2.y), packh2(f2.z, f2.w),
                                  packh2(f3.x, f3.y), packh2(f3.z, f3.w));
            int g0 = seg * 2, g1 = seg * 2 + 1;
            int gs0 = (g0 & 24) | ((g0 ^ t_idx) & 7);
            int gs1 = (g1 & 24) | ((g1 ^ t_idx) & 7);
            *(uint4*)(smem + 65536 + t_idx * 512 + gs0 * 16) = h0;
            *(uint4*)(smem + 65536 + t_idx * 512 + gs1 * 16) = h1;
        }
        __syncthreads();

#pragma unroll
        for (int sub = 0; sub < 2; ++sub) {
            const int sblk = wave * 2 + sub;
            const int srow = sblk * 16 + fr;
            f32x4 sc = {0.f, 0.f, 0.f, 0.f};
#pragma unroll
            for (int ks2 = 0; ks2 < 8; ++ks2) {
                int kb = ks2 * 4 + quad;
                int ko = ((kb & 24) | ((kb ^ xr) & 7)) * 16;
                f16x8 ph = *(const f16x8*)(smem + srow * 512 + ko);
                f16x8 qh = *(const f16x8*)(smem + 65536 + fr * 512 + ko);
                sc = __builtin_amdgcn_mfma_f32_16x16x32_f16(qh, ph, sc, 0, 0, 0);
            }
            int sg = sbase + sblk * 16 + fr;
#pragma unroll
            for (int r = 0; r < 4; ++r) {
                int tloc = quad * 4 + r;
                if (tloc < nn) {
                    int tg = tl[tc + tloc];
                    bufs[((size_t)tg * B_ + b) * S_ + sg] = sc[r];
                }
            }
        }
        __syncthreads();
    }
}

// ---------------------------------------------------------------------------
// Masked softmax over complete logits (single buf).
// ---------------------------------------------------------------------------
__global__ __launch_bounds__(256) void softmax_kernel(
    const float* __restrict__ bufs, float* __restrict__ out,
    const int* __restrict__ mask) {
    const int row = blockIdx.x;
    const int b = row & (B_ - 1);
    const float* w0 = bufs + (size_t)row * S_;
    float* w = out + (size_t)row * S_;
    const int* mrow = mask + (size_t)b * S_;
    const int tid = threadIdx.x;

    float4 va = *(const float4*)(w0 + tid * 4);
    int4 mm = *(const int4*)(mrow + tid * 4);
    float x0 = mm.x ? -INFINITY : va.x;
    float x1 = mm.y ? -INFINITY : va.y;
    float x2 = mm.z ? -INFINITY : va.z;
    float x3 = mm.w ? -INFINITY : va.w;

    float lmax = fmaxf(fmaxf(x0, x1), fmaxf(x2, x3));
#pragma unroll
    for (int off = 32; off >= 1; off >>= 1)
        lmax = fmaxf(lmax, __shfl_down(lmax, off));

    __shared__ float redmax[4];
    __shared__ float redsum[4];
    const int wave = tid >> 6, lane = tid & 63;
    if (lane == 0) redmax[wave] = lmax;
    __syncthreads();
    float gmax = fmaxf(fmaxf(redmax[0], redmax[1]), fmaxf(redmax[2], redmax[3]));

    float e0 = mm.x ? 0.f : __expf(x0 - gmax);
    float e1 = mm.y ? 0.f : __expf(x1 - gmax);
    float e2 = mm.z ? 0.f : __expf(x2 - gmax);
    float e3 = mm.w ? 0.f : __expf(x3 - gmax);
    float lsum = e0 + e1 + e2 + e3;
#pragma unroll
    for (int off = 32; off >= 1; off >>= 1)
        lsum += __shfl_down(lsum, off);
    if (lane == 0) redsum[wave] = lsum;
    __syncthreads();
    float gsum = redsum[0] + redsum[1] + redsum[2] + redsum[3];
    float rinv = 1.0f / gsum;

    *(float4*)(w + tid * 4) = make_float4(e0 * rinv, e1 * rinv, e2 * rinv, e3 * rinv);
}

// ---------------------------------------------------------------------------
extern "C" void kernel_launch(void* const* d_in, const int* in_sizes, int n_in,
                              void* d_out, int out_size, void* d_ws, size_t ws_size,
                              hipStream_t stream) {
    const float* src = (const float*)d_in[0];    // (B,S,E) fp32 — READ-ONLY now
    const int* mask = (const int*)d_in[1];       // (B,S)
    const float* qv = (const float*)d_in[2];     // (T,B,Q) fp32
    float* Wsrc = (float*)d_in[3];               // (H*Q,E) — fp16-packed in place
    const float* Wopt = (const float*)d_in[4];   // (H,Q)
    float* out = (float*)d_out;                  // (T,B,S)

    // ws: bufs = (T,B,S) logits (16 MiB), then best[] (T*B ints)
    float* bufs = (float*)d_ws;
    int* best = (int*)((char*)d_ws + (size_t)T_ * B_ * S_ * sizeof(float));

    hipLaunchKernelGGL(prep_kernel, dim3(WW_BLOCKS + HS_BLOCKS), dim3(256),
                       0, stream, Wsrc, qv, Wopt, best);
    hipLaunchKernelGGL(proj_score_kernel, dim3(1024), dim3(256), 0, stream,
                       src, (const unsigned char*)Wsrc,
                       qv, best, bufs);
    hipLaunchKernelGGL(softmax_kernel, dim3(T_ * B_), dim3(256), 0, stream,
                       bufs, out, mask);
}

// Round 14
// 165.314 us; speedup vs baseline: 1.2015x; 1.2015x over previous
//
#include <hip/hip_runtime.h>
#include <hip/hip_bf16.h>
#include <math.h>

#define B_ 32
#define S_ 1024
#define E_ 512
#define T_ 128
#define Q_ 256
#define H_ 4
#define F_ (H_ * Q_)      // 1024
#define M_ (B_ * S_)      // 32768

typedef _Float16 f16x8 __attribute__((ext_vector_type(8)));
typedef float f32x4 __attribute__((ext_vector_type(4)));
typedef unsigned int uint32;

__device__ __forceinline__ float lrelu(float x) { return x > 0.0f ? x : 0.01f * x; }

__device__ __forceinline__ uint32 packh2(float a, float b) {
    union { _Float16 h[2]; uint32 u; } v;
    v.h[0] = (_Float16)a; v.h[1] = (_Float16)b;
    return v.u;
}
__device__ __forceinline__ unsigned short packh1(float a) {
    union { _Float16 h; unsigned short u; } v;
    v.h = (_Float16)a;
    return v.u;
}

#define GLOAD_LDS16(g, l)                                                       \
    __builtin_amdgcn_global_load_lds(                                           \
        (const __attribute__((address_space(1))) void*)(g),                     \
        (__attribute__((address_space(3))) void*)(l), 16, 0, 0)

#define SRC_BLOCKS 16384      // src windows / 16 (r8 prep form: 16 lanes/window)
#define W_BLOCKS   512        // W_src windows / 16
#define HS_BLOCKS  1024       // head-select: wave per (t,b), 4 waves/block

// ---------------------------------------------------------------------------
// Prep (r8-verbatim form — measured better than r9's 4-lane variant):
// pack src/W_src IN PLACE to fp16 (RTN) per 64-float window (64 fp16 in the
// window's first 128B). 16 lanes/window: each lane reads its own float4 and
// writes its own uint2; wave-lockstep loads retire before the store issues
// -> in-place-safe. + per-(t,b) argmax head into best[].
// ---------------------------------------------------------------------------
__global__ __launch_bounds__(256) void prep_kernel(
    float* src, float* wsrc,
    const float* __restrict__ qv, const float* __restrict__ Wopt,
    int* __restrict__ best) {
    const int blk = blockIdx.x;
    if (blk < SRC_BLOCKS + W_BLOCKS) {
        float* base = (blk < SRC_BLOCKS) ? src : wsrc;
        const size_t woff = (size_t)((blk < SRC_BLOCKS) ? blk : (blk - SRC_BLOCKS)) * 16;
        const int tid = threadIdx.x;
        const size_t c = woff + (tid >> 4);
        const int j = tid & 15;
        float* wp = base + c * 64;
        float4 v = *(const float4*)(wp + j * 4);
        uint2 o = make_uint2(packh2(v.x, v.y), packh2(v.z, v.w));
        *(uint2*)((char*)wp + j * 8) = o;
    } else {
        const int wave = threadIdx.x >> 6, lane = threadIdx.x & 63;
        const int idx = (blk - SRC_BLOCKS - W_BLOCKS) * 4 + wave;   // t*B + b
        const float4 qq = *(const float4*)(qv + (size_t)idx * Q_ + lane * 4);
        float s[4];
#pragma unroll
        for (int h = 0; h < 4; ++h) {
            float4 w = *(const float4*)(Wopt + h * Q_ + lane * 4);
            s[h] = qq.x * w.x + qq.y * w.y + qq.z * w.z + qq.w * w.w;
        }
#pragma unroll
        for (int off = 32; off >= 1; off >>= 1) {
#pragma unroll
            for (int h = 0; h < 4; ++h) s[h] += __shfl_down(s[h], off);
        }
        if (lane == 0) {
            int bh = 0; float bs = s[0];
            if (s[1] > bs) { bs = s[1]; bh = 1; }
            if (s[2] > bs) { bs = s[2]; bh = 2; }
            if (s[3] > bs) { bs = s[3]; bh = 3; }
            best[idx] = bh;
        }
    }
}

// ---------------------------------------------------------------------------
// Fused proj+score (r9-verbatim — 53.2 us, MfmaUtil 27, verified): fp16,
// 128x256 tile = FULL HEAD per block. 4 waves, wave-tile 64x128, acc[4][8].
// K-loop: counted-vmcnt dbuf, 6 gload_lds/wave/step (A 2 + B 4) -> vmcnt(6).
// 2-bit XOR swizzle on 64B rows (pre-swizzled source = swizzled read).
// Epilogue: single P (128 rows x 512B, 5-bit granule swizzle), full-Q score,
// single output buf. A-direct variants measured SLOWER (r12: +14, r13: +54).
// ---------------------------------------------------------------------------
__global__ __launch_bounds__(256, 2) void proj_score_kernel(
    const unsigned char* __restrict__ Apk,   // fp16-packed src (windowed)
    const unsigned char* __restrict__ Wpk,   // fp16-packed W_src (windowed)
    const float* __restrict__ qv,            // (T,B,Q) fp32
    const int* __restrict__ best,            // (T*B)
    float* __restrict__ bufs)                // (T,B,S) logits in ws
{
    __shared__ uint4 smem4[4800];            // 76800 B
    char* smem = (char*)smem4;
    // K-loop dbuf: buf@0, buf@24576; each 24KB: A[0,8K) B[8K,24K)
    // Epilogue: P @0 (128 rows x 512B = 64KB)  Q @65536 (16 rows x 512B = 8KB)
    //           tl @73728 (+512)  lcnt @74240

    const int bid = blockIdx.x;
    const int xcd = bid & 7;
    const int q_ = bid >> 3;                 // 0..127 within XCD
    const int bi = xcd * 32 + (q_ >> 2);     // 0..255 (M tile, 128 rows)
    const int bj = q_ & 3;                   // head 0..3 (N tile, 256 cols)

    const int tid = threadIdx.x;
    const int wave = tid >> 6, lane = tid & 63;
    const int wm = wave >> 1, wn = wave & 1;
    const int quad = lane >> 4;
    const int fr = lane & 15;
    const int xr = fr & 7;

    const size_t Abase = (size_t)(bi * 128) * 2048;
    const size_t Wbase = (size_t)(bj * 256) * 2048;

    // --- staging lane mapping (16 rows x 4 slots per wave-instr) ---
    const int r16 = lane >> 2;
    const int slot = lane & 3;
    const int sgb = ((slot ^ ((r16 >> 1) & 3)) & 3) * 16;  // pre-swizzled src group
    const unsigned char* gA = Apk + Abase + (size_t)(wave * 32 + r16) * 2048 + sgb;
    const unsigned char* gW = Wpk + Wbase + (size_t)(wave * 64 + r16) * 2048 + sgb;

    // --- compute lane mapping ---
    const int koB = ((quad ^ ((fr >> 1) & 3)) & 3) * 16;   // swizzled read slot
    const int aoff = (wm * 64 + fr) * 64 + koB;
    const int boff = (wn * 128 + fr) * 64 + koB;

    f32x4 acc[4][8] = {};

#define STAGE(bufb_, ks_) do {                                                 \
    const int hb_ = ((ks_) >> 1) * 256 + ((ks_) & 1) * 64;                     \
    _Pragma("unroll")                                                          \
    for (int c_ = 0; c_ < 2; ++c_) {                                           \
        GLOAD_LDS16(gA + (size_t)c_ * 16 * 2048 + hb_,                         \
                    smem + (bufb_) + (wave * 2 + c_) * 1024);                  \
    }                                                                          \
    _Pragma("unroll")                                                          \
    for (int c_ = 0; c_ < 4; ++c_) {                                           \
        GLOAD_LDS16(gW + (size_t)c_ * 16 * 2048 + hb_,                         \
                    smem + (bufb_) + 8192 + (wave * 4 + c_) * 1024);           \
    }                                                                          \
} while (0)

    STAGE(0, 0);
    STAGE(24576, 1);
    asm volatile("s_waitcnt vmcnt(6)" ::: "memory");   // batch 0 landed (b1 in flight)
    __builtin_amdgcn_s_barrier();

    int cur = 0;
#pragma unroll 1
    for (int ks = 0; ks < 16; ++ks) {
        f16x8 ah[4], bh8[8];
#pragma unroll
        for (int i_ = 0; i_ < 4; ++i_)
            ah[i_] = *(const f16x8*)(smem + cur + aoff + i_ * 1024);
#pragma unroll
        for (int j_ = 0; j_ < 8; ++j_)
            bh8[j_] = *(const f16x8*)(smem + cur + 8192 + boff + j_ * 1024);
        asm volatile("s_waitcnt lgkmcnt(0)" ::: "memory");  // my reads of cur done
        __builtin_amdgcn_s_barrier();                       // everyone's reads done
        if (ks < 14) STAGE(cur, ks + 2);                    // overwrite cur (prefetch)
        __builtin_amdgcn_s_setprio(1);
#pragma unroll
        for (int i_ = 0; i_ < 4; ++i_)
#pragma unroll
            for (int j_ = 0; j_ < 8; ++j_) {
                acc[i_][j_] = __builtin_amdgcn_mfma_f32_16x16x32_f16(ah[i_], bh8[j_], acc[i_][j_], 0, 0, 0);
            }
        __builtin_amdgcn_s_setprio(0);
        if (ks < 14) {
            asm volatile("s_waitcnt vmcnt(6)" ::: "memory"); // batch ks+1 landed
        } else if (ks == 14) {
            asm volatile("s_waitcnt vmcnt(0)" ::: "memory"); // final batch landed
        }
        if (ks < 15) __builtin_amdgcn_s_barrier();           // next buffer ready
        cur ^= 24576;
    }

#undef STAGE

    // ---- fused score epilogue (full head -> final logits, single buf) ----
    const int b = bi >> 3;
    const int sbase = (bi & 7) * 128;

    __syncthreads();                       // K-loop LDS reads done
    int* tl = (int*)(smem + 73728);
    int* lcnt = (int*)(smem + 74240);
    if (tid == 0) *lcnt = 0;
    __syncthreads();
    if (tid < 128) {
        if (best[tid * B_ + b] == bj) {
            int slot2 = atomicAdd(lcnt, 1);   // LDS atomic
            tl[slot2] = tid;
        }
    }
    __syncthreads();
    const int n = *lcnt;

    // P write: every wave writes its own acc (P covers all 128 rows at once)
#pragma unroll
    for (int i = 0; i < 4; ++i) {
#pragma unroll
        for (int j = 0; j < 8; ++j) {
            int col = wn * 128 + j * 16 + fr;
            int g = col >> 3;
            int cb = (col & 7) * 2;
#pragma unroll
            for (int r = 0; r < 4; ++r) {
                int rr = wm * 64 + i * 16 + quad * 4 + r;
                int gs = (g & 24) | ((g ^ rr) & 7);
                *(unsigned short*)(smem + rr * 512 + gs * 16 + cb) =
                    packh1(lrelu(acc[i][j][r]));
            }
        }
    }
    __syncthreads();

    const int t_idx = tid >> 4, seg = tid & 15;

    for (int tc = 0; tc < n; tc += 16) {
        int nn = min(16, n - tc);
        if (t_idx < nn) {
            int tt = tl[tc + t_idx];
            const float* qp = qv + ((size_t)tt * B_ + b) * Q_ + seg * 16;
            float4 f0 = *(const float4*)(qp);
            float4 f1 = *(const float4*)(qp + 4);
            float4 f2 = *(const float4*)(qp + 8);
            float4 f3 = *(const float4*)(qp + 12);
            uint4 h0 = make_uint4(packh2(f0.x, f0.y), packh2(f0.z, f0.w),
                                  packh2(f1.x, f1.y), packh2(f1.z, f1.w));
            uint4 h1 = make_uint4(packh2(f2.x, f2.y), packh2(f2.z, f2.w),
                                  packh2(f3.x, f3.y), packh2(f3.z, f3.w));
            int g0 = seg * 2, g1 = seg * 2 + 1;
            int gs0 = (g0 & 24) | ((g0 ^ t_idx) & 7);
            int gs1 = (g1 & 24) | ((g1 ^ t_idx) & 7);
            *(uint4*)(smem + 65536 + t_idx * 512 + gs0 * 16) = h0;
            *(uint4*)(smem + 65536 + t_idx * 512 + gs1 * 16) = h1;
        }
        __syncthreads();

#pragma unroll
        for (int sub = 0; sub < 2; ++sub) {
            const int sblk = wave * 2 + sub;
            const int srow = sblk * 16 + fr;
            f32x4 sc = {0.f, 0.f, 0.f, 0.f};
#pragma unroll
            for (int ks2 = 0; ks2 < 8; ++ks2) {
                int kb = ks2 * 4 + quad;
                int ko = ((kb & 24) | ((kb ^ xr) & 7)) * 16;
                f16x8 ph = *(const f16x8*)(smem + srow * 512 + ko);
                f16x8 qh = *(const f16x8*)(smem + 65536 + fr * 512 + ko);
                sc = __builtin_amdgcn_mfma_f32_16x16x32_f16(qh, ph, sc, 0, 0, 0);
            }
            int sg = sbase + sblk * 16 + fr;
#pragma unroll
            for (int r = 0; r < 4; ++r) {
                int tloc = quad * 4 + r;
                if (tloc < nn) {
                    int tg = tl[tc + tloc];
                    bufs[((size_t)tg * B_ + b) * S_ + sg] = sc[r];
                }
            }
        }
        __syncthreads();
    }
}

// ---------------------------------------------------------------------------
// Masked softmax over complete logits (single buf).
// ---------------------------------------------------------------------------
__global__ __launch_bounds__(256) void softmax_kernel(
    const float* __restrict__ bufs, float* __restrict__ out,
    const int* __restrict__ mask) {
    const int row = blockIdx.x;
    const int b = row & (B_ - 1);
    const float* w0 = bufs + (size_t)row * S_;
    float* w = out + (size_t)row * S_;
    const int* mrow = mask + (size_t)b * S_;
    const int tid = threadIdx.x;

    float4 va = *(const float4*)(w0 + tid * 4);
    int4 mm = *(const int4*)(mrow + tid * 4);
    float x0 = mm.x ? -INFINITY : va.x;
    float x1 = mm.y ? -INFINITY : va.y;
    float x2 = mm.z ? -INFINITY : va.z;
    float x3 = mm.w ? -INFINITY : va.w;

    float lmax = fmaxf(fmaxf(x0, x1), fmaxf(x2, x3));
#pragma unroll
    for (int off = 32; off >= 1; off >>= 1)
        lmax = fmaxf(lmax, __shfl_down(lmax, off));

    __shared__ float redmax[4];
    __shared__ float redsum[4];
    const int wave = tid >> 6, lane = tid & 63;
    if (lane == 0) redmax[wave] = lmax;
    __syncthreads();
    float gmax = fmaxf(fmaxf(redmax[0], redmax[1]), fmaxf(redmax[2], redmax[3]));

    float e0 = mm.x ? 0.f : __expf(x0 - gmax);
    float e1 = mm.y ? 0.f : __expf(x1 - gmax);
    float e2 = mm.z ? 0.f : __expf(x2 - gmax);
    float e3 = mm.w ? 0.f : __expf(x3 - gmax);
    float lsum = e0 + e1 + e2 + e3;
#pragma unroll
    for (int off = 32; off >= 1; off >>= 1)
        lsum += __shfl_down(lsum, off);
    if (lane == 0) redsum[wave] = lsum;
    __syncthreads();
    float gsum = redsum[0] + redsum[1] + redsum[2] + redsum[3];
    float rinv = 1.0f / gsum;

    *(float4*)(w + tid * 4) = make_float4(e0 * rinv, e1 * rinv, e2 * rinv, e3 * rinv);
}

// ---------------------------------------------------------------------------
extern "C" void kernel_launch(void* const* d_in, const int* in_sizes, int n_in,
                              void* d_out, int out_size, void* d_ws, size_t ws_size,
                              hipStream_t stream) {
    float* src  = (float*)d_in[0];               // (B,S,E) — fp16-packed in place
    const int* mask = (const int*)d_in[1];       // (B,S)
    const float* qv = (const float*)d_in[2];     // (T,B,Q) fp32
    float* Wsrc = (float*)d_in[3];               // (H*Q,E) — fp16-packed in place
    const float* Wopt = (const float*)d_in[4];   // (H,Q)
    float* out = (float*)d_out;                  // (T,B,S)

    // ws: bufs = (T,B,S) logits (16 MiB), then best[] (T*B ints)
    float* bufs = (float*)d_ws;
    int* best = (int*)((char*)d_ws + (size_t)T_ * B_ * S_ * sizeof(float));

    hipLaunchKernelGGL(prep_kernel, dim3(SRC_BLOCKS + W_BLOCKS + HS_BLOCKS), dim3(256),
                       0, stream, src, Wsrc, qv, Wopt, best);
    hipLaunchKernelGGL(proj_score_kernel, dim3(1024), dim3(256), 0, stream,
                       (const unsigned char*)src, (const unsigned char*)Wsrc,
                       qv, best, bufs);
    hipLaunchKernelGGL(softmax_kernel, dim3(T_ * B_), dim3(256), 0, stream,
                       bufs, out, mask);
}

// Round 16
// 158.690 us; speedup vs baseline: 1.2517x; 1.0417x over previous
//
#include <hip/hip_runtime.h>
#include <hip/hip_bf16.h>
#include <math.h>

#define B_ 32
#define S_ 1024
#define E_ 512
#define T_ 128
#define Q_ 256
#define H_ 4
#define F_ (H_ * Q_)      // 1024
#define M_ (B_ * S_)      // 32768

typedef _Float16 f16x8 __attribute__((ext_vector_type(8)));
typedef float f32x4 __attribute__((ext_vector_type(4)));
typedef unsigned int uint32;

__device__ __forceinline__ float lrelu(float x) { return x > 0.0f ? x : 0.01f * x; }

__device__ __forceinline__ uint32 packh2(float a, float b) {
    union { _Float16 h[2]; uint32 u; } v;
    v.h[0] = (_Float16)a; v.h[1] = (_Float16)b;
    return v.u;
}
__device__ __forceinline__ unsigned short packh1(float a) {
    union { _Float16 h; unsigned short u; } v;
    v.h = (_Float16)a;
    return v.u;
}

#define GLOAD_LDS16(g, l)                                                       \
    __builtin_amdgcn_global_load_lds(                                           \
        (const __attribute__((address_space(1))) void*)(g),                     \
        (__attribute__((address_space(3))) void*)(l), 16, 0, 0)

#define PACK_BLOCKS 2048      // grid-strided pack (Guideline 11: cap + stride)
#define SRC_CHUNKS  16384     // src windows / 16  (32*1024*512/64 = 262144 windows)
#define PACK_CHUNKS 16896     // + W_src windows / 16 = 512  (8192 windows) [r15 bug: was 17408 -> OOB]
#define HS_BLOCKS   1024      // head-select: wave per (t,b), 4 waves/block

// ---------------------------------------------------------------------------
// Prep: pack src/W_src IN PLACE to fp16 (RTN) per 64-float window (64 fp16 in
// the window's first 128B). 16 lanes/window (r8/r14-verified form),
// GRID-STRIDED over 2048 blocks (~8-9 chunks of 16 windows each) instead of
// 16896 one-shot blocks. In-place safety unchanged: each wave's read->write
// stays within its own disjoint windows per iteration; iterations touch
// disjoint chunks. + per-(t,b) argmax head into best[].
// r15 crash root cause: PACK_CHUNKS over-counted W chunks (1024 vs 512) ->
// 2MB OOB writes past Wsrc. Fixed constant only; structure unchanged.
// ---------------------------------------------------------------------------
__global__ __launch_bounds__(256) void prep_kernel(
    float* src, float* wsrc,
    const float* __restrict__ qv, const float* __restrict__ Wopt,
    int* __restrict__ best) {
    const int blk = blockIdx.x;
    if (blk < PACK_BLOCKS) {
        const int tid = threadIdx.x;
        const int wsub = tid >> 4;       // window within chunk (0..15)
        const int j = tid & 15;          // 4-float group within window
#pragma unroll 1
        for (int c = blk; c < PACK_CHUNKS; c += PACK_BLOCKS) {
            float* base;
            size_t w0;
            if (c < SRC_CHUNKS) { base = src;  w0 = (size_t)c * 16; }
            else                { base = wsrc; w0 = (size_t)(c - SRC_CHUNKS) * 16; }
            float* wp = base + (w0 + wsub) * 64;
            float4 v = *(const float4*)(wp + j * 4);
            uint2 o = make_uint2(packh2(v.x, v.y), packh2(v.z, v.w));
            *(uint2*)((char*)wp + j * 8) = o;
        }
    } else {
        const int wave = threadIdx.x >> 6, lane = threadIdx.x & 63;
        const int idx = (blk - PACK_BLOCKS) * 4 + wave;   // t*B + b
        const float4 qq = *(const float4*)(qv + (size_t)idx * Q_ + lane * 4);
        float s[4];
#pragma unroll
        for (int h = 0; h < 4; ++h) {
            float4 w = *(const float4*)(Wopt + h * Q_ + lane * 4);
            s[h] = qq.x * w.x + qq.y * w.y + qq.z * w.z + qq.w * w.w;
        }
#pragma unroll
        for (int off = 32; off >= 1; off >>= 1) {
#pragma unroll
            for (int h = 0; h < 4; ++h) s[h] += __shfl_down(s[h], off);
        }
        if (lane == 0) {
            int bh = 0; float bs = s[0];
            if (s[1] > bs) { bs = s[1]; bh = 1; }
            if (s[2] > bs) { bs = s[2]; bh = 2; }
            if (s[3] > bs) { bs = s[3]; bh = 3; }
            best[idx] = bh;
        }
    }
}

// ---------------------------------------------------------------------------
// Fused proj+score (r14-verbatim — 53.5 us, MfmaUtil 27-28, verified): fp16,
// 128x256 tile = FULL HEAD per block. 4 waves, wave-tile 64x128, acc[4][8].
// K-loop: counted-vmcnt dbuf, 6 gload_lds/wave/step (A 2 + B 4) -> vmcnt(6).
// 2-bit XOR swizzle on 64B rows (pre-swizzled source = swizzled read).
// Epilogue: single P (128 rows x 512B, 5-bit granule swizzle), full-Q score,
// single output buf. A-direct variants measured SLOWER (r12: +14, r13: +54).
// ---------------------------------------------------------------------------
__global__ __launch_bounds__(256, 2) void proj_score_kernel(
    const unsigned char* __restrict__ Apk,   // fp16-packed src (windowed)
    const unsigned char* __restrict__ Wpk,   // fp16-packed W_src (windowed)
    const float* __restrict__ qv,            // (T,B,Q) fp32
    const int* __restrict__ best,            // (T*B)
    float* __restrict__ bufs)                // (T,B,S) logits in ws
{
    __shared__ uint4 smem4[4800];            // 76800 B
    char* smem = (char*)smem4;
    // K-loop dbuf: buf@0, buf@24576; each 24KB: A[0,8K) B[8K,24K)
    // Epilogue: P @0 (128 rows x 512B = 64KB)  Q @65536 (16 rows x 512B = 8KB)
    //           tl @73728 (+512)  lcnt @74240

    const int bid = blockIdx.x;
    const int xcd = bid & 7;
    const int q_ = bid >> 3;                 // 0..127 within XCD
    const int bi = xcd * 32 + (q_ >> 2);     // 0..255 (M tile, 128 rows)
    const int bj = q_ & 3;                   // head 0..3 (N tile, 256 cols)

    const int tid = threadIdx.x;
    const int wave = tid >> 6, lane = tid & 63;
    const int wm = wave >> 1, wn = wave & 1;
    const int quad = lane >> 4;
    const int fr = lane & 15;
    const int xr = fr & 7;

    const size_t Abase = (size_t)(bi * 128) * 2048;
    const size_t Wbase = (size_t)(bj * 256) * 2048;

    // --- staging lane mapping (16 rows x 4 slots per wave-instr) ---
    const int r16 = lane >> 2;
    const int slot = lane & 3;
    const int sgb = ((slot ^ ((r16 >> 1) & 3)) & 3) * 16;  // pre-swizzled src group
    const unsigned char* gA = Apk + Abase + (size_t)(wave * 32 + r16) * 2048 + sgb;
    const unsigned char* gW = Wpk + Wbase + (size_t)(wave * 64 + r16) * 2048 + sgb;

    // --- compute lane mapping ---
    const int koB = ((quad ^ ((fr >> 1) & 3)) & 3) * 16;   // swizzled read slot
    const int aoff = (wm * 64 + fr) * 64 + koB;
    const int boff = (wn * 128 + fr) * 64 + koB;

    f32x4 acc[4][8] = {};

#define STAGE(bufb_, ks_) do {                                                 \
    const int hb_ = ((ks_) >> 1) * 256 + ((ks_) & 1) * 64;                     \
    _Pragma("unroll")                                                          \
    for (int c_ = 0; c_ < 2; ++c_) {                                           \
        GLOAD_LDS16(gA + (size_t)c_ * 16 * 2048 + hb_,                         \
                    smem + (bufb_) + (wave * 2 + c_) * 1024);                  \
    }                                                                          \
    _Pragma("unroll")                                                          \
    for (int c_ = 0; c_ < 4; ++c_) {                                           \
        GLOAD_LDS16(gW + (size_t)c_ * 16 * 2048 + hb_,                         \
                    smem + (bufb_) + 8192 + (wave * 4 + c_) * 1024);           \
    }                                                                          \
} while (0)

    STAGE(0, 0);
    STAGE(24576, 1);
    asm volatile("s_waitcnt vmcnt(6)" ::: "memory");   // batch 0 landed (b1 in flight)
    __builtin_amdgcn_s_barrier();

    int cur = 0;
#pragma unroll 1
    for (int ks = 0; ks < 16; ++ks) {
        f16x8 ah[4], bh8[8];
#pragma unroll
        for (int i_ = 0; i_ < 4; ++i_)
            ah[i_] = *(const f16x8*)(smem + cur + aoff + i_ * 1024);
#pragma unroll
        for (int j_ = 0; j_ < 8; ++j_)
            bh8[j_] = *(const f16x8*)(smem + cur + 8192 + boff + j_ * 1024);
        asm volatile("s_waitcnt lgkmcnt(0)" ::: "memory");  // my reads of cur done
        __builtin_amdgcn_s_barrier();                       // everyone's reads done
        if (ks < 14) STAGE(cur, ks + 2);                    // overwrite cur (prefetch)
        __builtin_amdgcn_s_setprio(1);
#pragma unroll
        for (int i_ = 0; i_ < 4; ++i_)
#pragma unroll
            for (int j_ = 0; j_ < 8; ++j_) {
                acc[i_][j_] = __builtin_amdgcn_mfma_f32_16x16x32_f16(ah[i_], bh8[j_], acc[i_][j_], 0, 0, 0);
            }
        __builtin_amdgcn_s_setprio(0);
        if (ks < 14) {
            asm volatile("s_waitcnt vmcnt(6)" ::: "memory"); // batch ks+1 landed
        } else if (ks == 14) {
            asm volatile("s_waitcnt vmcnt(0)" ::: "memory"); // final batch landed
        }
        if (ks < 15) __builtin_amdgcn_s_barrier();           // next buffer ready
        cur ^= 24576;
    }

#undef STAGE

    // ---- fused score epilogue (full head -> final logits, single buf) ----
    const int b = bi >> 3;
    const int sbase = (bi & 7) * 128;

    __syncthreads();                       // K-loop LDS reads done
    int* tl = (int*)(smem + 73728);
    int* lcnt = (int*)(smem + 74240);
    if (tid == 0) *lcnt = 0;
    __syncthreads();
    if (tid < 128) {
        if (best[tid * B_ + b] == bj) {
            int slot2 = atomicAdd(lcnt, 1);   // LDS atomic
            tl[slot2] = tid;
        }
    }
    __syncthreads();
    const int n = *lcnt;

    // P write: every wave writes its own acc (P covers all 128 rows at once)
#pragma unroll
    for (int i = 0; i < 4; ++i) {
#pragma unroll
        for (int j = 0; j < 8; ++j) {
            int col = wn * 128 + j * 16 + fr;
            int g = col >> 3;
            int cb = (col & 7) * 2;
#pragma unroll
            for (int r = 0; r < 4; ++r) {
                int rr = wm * 64 + i * 16 + quad * 4 + r;
                int gs = (g & 24) | ((g ^ rr) & 7);
                *(unsigned short*)(smem + rr * 512 + gs * 16 + cb) =
                    packh1(lrelu(acc[i][j][r]));
            }
        }
    }
    __syncthreads();

    const int t_idx = tid >> 4, seg = tid & 15;

    for (int tc = 0; tc < n; tc += 16) {
        int nn = min(16, n - tc);
        if (t_idx < nn) {
            int tt = tl[tc + t_idx];
            const float* qp = qv + ((size_t)tt * B_ + b) * Q_ + seg * 16;
            float4 f0 = *(const float4*)(qp);
            float4 f1 = *(const float4*)(qp + 4);
            float4 f2 = *(const float4*)(qp + 8);
            float4 f3 = *(const float4*)(qp + 12);
            uint4 h0 = make_uint4(packh2(f0.x, f0.y), packh2(f0.z, f0.w),
                                  packh2(f1.x, f1.y), packh2(f1.z, f1.w));
            uint4 h1 = make_uint4(packh2(f2.x, f2.y), packh2(f2.z, f2.w),
                                  packh2(f3.x, f3.y), packh2(f3.z, f3.w));
            int g0 = seg * 2, g1 = seg * 2 + 1;
            int gs0 = (g0 & 24) | ((g0 ^ t_idx) & 7);
            int gs1 = (g1 & 24) | ((g1 ^ t_idx) & 7);
            *(uint4*)(smem + 65536 + t_idx * 512 + gs0 * 16) = h0;
            *(uint4*)(smem + 65536 + t_idx * 512 + gs1 * 16) = h1;
        }
        __syncthreads();

#pragma unroll
        for (int sub = 0; sub < 2; ++sub) {
            const int sblk = wave * 2 + sub;
            const int srow = sblk * 16 + fr;
            f32x4 sc = {0.f, 0.f, 0.f, 0.f};
#pragma unroll
            for (int ks2 = 0; ks2 < 8; ++ks2) {
                int kb = ks2 * 4 + quad;
                int ko = ((kb & 24) | ((kb ^ xr) & 7)) * 16;
                f16x8 ph = *(const f16x8*)(smem + srow * 512 + ko);
                f16x8 qh = *(const f16x8*)(smem + 65536 + fr * 512 + ko);
                sc = __builtin_amdgcn_mfma_f32_16x16x32_f16(qh, ph, sc, 0, 0, 0);
            }
            int sg = sbase + sblk * 16 + fr;
#pragma unroll
            for (int r = 0; r < 4; ++r) {
                int tloc = quad * 4 + r;
                if (tloc < nn) {
                    int tg = tl[tc + tloc];
                    bufs[((size_t)tg * B_ + b) * S_ + sg] = sc[r];
                }
            }
        }
        __syncthreads();
    }
}

// ---------------------------------------------------------------------------
// Masked softmax over complete logits (single buf).
// ---------------------------------------------------------------------------
__global__ __launch_bounds__(256) void softmax_kernel(
    const float* __restrict__ bufs, float* __restrict__ out,
    const int* __restrict__ mask) {
    const int row = blockIdx.x;
    const int b = row & (B_ - 1);
    const float* w0 = bufs + (size_t)row * S_;
    float* w = out + (size_t)row * S_;
    const int* mrow = mask + (size_t)b * S_;
    const int tid = threadIdx.x;

    float4 va = *(const float4*)(w0 + tid * 4);
    int4 mm = *(const int4*)(mrow + tid * 4);
    float x0 = mm.x ? -INFINITY : va.x;
    float x1 = mm.y ? -INFINITY : va.y;
    float x2 = mm.z ? -INFINITY : va.z;
    float x3 = mm.w ? -INFINITY : va.w;

    float lmax = fmaxf(fmaxf(x0, x1), fmaxf(x2, x3));
#pragma unroll
    for (int off = 32; off >= 1; off >>= 1)
        lmax = fmaxf(lmax, __shfl_down(lmax, off));

    __shared__ float redmax[4];
    __shared__ float redsum[4];
    const int wave = tid >> 6, lane = tid & 63;
    if (lane == 0) redmax[wave] = lmax;
    __syncthreads();
    float gmax = fmaxf(fmaxf(redmax[0], redmax[1]), fmaxf(redmax[2], redmax[3]));

    float e0 = mm.x ? 0.f : __expf(x0 - gmax);
    float e1 = mm.y ? 0.f : __expf(x1 - gmax);
    float e2 = mm.z ? 0.f : __expf(x2 - gmax);
    float e3 = mm.w ? 0.f : __expf(x3 - gmax);
    float lsum = e0 + e1 + e2 + e3;
#pragma unroll
    for (int off = 32; off >= 1; off >>= 1)
        lsum += __shfl_down(lsum, off);
    if (lane == 0) redsum[wave] = lsum;
    __syncthreads();
    float gsum = redsum[0] + redsum[1] + redsum[2] + redsum[3];
    float rinv = 1.0f / gsum;

    *(float4*)(w + tid * 4) = make_float4(e0 * rinv, e1 * rinv, e2 * rinv, e3 * rinv);
}

// ---------------------------------------------------------------------------
extern "C" void kernel_launch(void* const* d_in, const int* in_sizes, int n_in,
                              void* d_out, int out_size, void* d_ws, size_t ws_size,
                              hipStream_t stream) {
    float* src  = (float*)d_in[0];               // (B,S,E) — fp16-packed in place
    const int* mask = (const int*)d_in[1];       // (B,S)
    const float* qv = (const float*)d_in[2];     // (T,B,Q) fp32
    float* Wsrc = (float*)d_in[3];               // (H*Q,E) — fp16-packed in place
    const float* Wopt = (const float*)d_in[4];   // (H,Q)
    float* out = (float*)d_out;                  // (T,B,S)

    // ws: bufs = (T,B,S) logits (16 MiB), then best[] (T*B ints)
    float* bufs = (float*)d_ws;
    int* best = (int*)((char*)d_ws + (size_t)T_ * B_ * S_ * sizeof(float));

    hipLaunchKernelGGL(prep_kernel, dim3(PACK_BLOCKS + HS_BLOCKS), dim3(256),
                       0, stream, src, Wsrc, qv, Wopt, best);
    hipLaunchKernelGGL(proj_score_kernel, dim3(1024), dim3(256), 0, stream,
                       (const unsigned char*)src, (const unsigned char*)Wsrc,
                       qv, best, bufs);
    hipLaunchKernelGGL(softmax_kernel, dim3(T_ * B_), dim3(256), 0, stream,
                       bufs, out, mask);
}